// Round 9
// baseline (123.235 us; speedup 1.0000x reference)
//
#include <hip/hip_runtime.h>
#include <hip/hip_bf16.h>

// Problem constants
static constexpr int Bn = 8, Cn = 128, Hn = 64, Wn = 64, Con = 128;
static constexpr int KKn = 9, DGn = 2, Cgn = 64;
static constexpr int HOn = 64, WOn = 64;
static constexpr int PITCH = 72;     // bf16 row pitch for s_val rows
static constexpr int OMP3 = 66;      // s_om row pitch (shorts), 64 pos + pad

typedef short short8 __attribute__((ext_vector_type(8)));
typedef float f32x4  __attribute__((ext_vector_type(4)));

__device__ __forceinline__ unsigned short f2bf(float f) {
    unsigned u = __float_as_uint(f);
    u += 0x7fff + ((u >> 16) & 1);          // round-to-nearest-even
    return (unsigned short)(u >> 16);
}
__device__ __forceinline__ float bf2f(unsigned short h) {
    return __uint_as_float(((unsigned)h) << 16);
}

// ---------------------------------------------------------------------------
// Kernel P: merged prep. R17: transpose LDS pitch 64 -> 65 (+1 pad) to break
// the 16-way read conflict (lane stride was 1024B = bank 0 for all lanes;
// now 1040B -> banks 4l mod 32, ~2-way).
// ---------------------------------------------------------------------------
__global__ __launch_bounds__(256) void prep(const float* __restrict__ x,
                                            const float* __restrict__ w,
                                            const float* __restrict__ ow,
                                            unsigned short* __restrict__ xt,
                                            unsigned short* __restrict__ wt2,
                                            unsigned short* __restrict__ owf) {
    __shared__ unsigned short s[128 * 65];       // padded [c][x]
    const int blk = blockIdx.x;
    const int t = threadIdx.x;
    if (blk < 512) {
        const int b = blk & 7, y = blk >> 3;
#pragma unroll
        for (int i = 0; i < 32; ++i) {
            int e = t + i * 256;                 // [0,8192)
            int c = e >> 6, xc = e & 63;
            s[c * 65 + xc] = f2bf(x[(((size_t)b * Cn + c) * Hn + y) * Wn + xc]);
        }
        __syncthreads();
        unsigned short* dst = xt + ((size_t)(b * 64 + y) * 64) * 128;
#pragma unroll
        for (int i = 0; i < 4; ++i) {
            int e = t + i * 256;                 // short8 id [0,1024)
            int xc = e >> 4;
            int c0 = (e & 15) * 8;
            short8 v;
#pragma unroll
            for (int j = 0; j < 8; ++j) v[j] = (short)s[(c0 + j) * 65 + xc];
            *(short8*)&dst[(size_t)e * 8] = v;
        }
    } else if (blk < 1088) {
        int e    = (blk - 512) * 256 + t;        // [0,147456)
        int j    = e & 7;
        int lane = (e >> 3) & 63;
        int tile = (e >> 9) & 7;
        int ks   = (e >> 12) & 1;
        int gk   = e >> 13;                      // 0..17
        int g = gk / 9, k = gk - g * 9;
        int oc = tile * 16 + (lane & 15);
        int c  = ks * 32 + (lane >> 4) * 8 + j;
        wt2[e] = f2bf(w[((size_t)oc * Cn + g * Cgn + c) * KKn + k]);
    } else {
        int e = (blk - 1088) * 256 + t;          // [0,36864)
        int g  = e / 18432;
        int r  = e - g * 18432;
        int ks = r >> 10;
        int r2 = r & 1023;
        int nt = r2 >> 9;
        int lane = (r2 >> 3) & 63;
        int j  = r2 & 7;
        int tap = ks >> 1, chalf = ks & 1;
        int oc_l = nt * 16 + (lane & 15);
        int c = chalf * 32 + (lane >> 4) * 8 + j;
        float v = 0.f;
        if (oc_l < 27)
            v = ow[((size_t)(g * 27 + oc_l) * Cgn + c) * KKn + tap];
        owf[e] = f2bf(v);
    }
}

// ---------------------------------------------------------------------------
// Kernel 2 (R17): LDS-window, PAIR-PROCESSED all-wave P2.
// R16 post-mortem: consumer diet null because producers were the long pole
// (consumers idled at the barrier). R17 removes specialization:
//   - gk processed in pairs: threads t<512 gather gk=2p -> buf0, t>=512
//     gather gk=2p+1 -> buf1 (same per-thread gather cost), barrier,
//     then ALL 16 waves MFMA both gk: wave = (rh4 = mt) x (np = oc-32).
//     Per gk per wave: 1 A ds_read x2ks shared across j, 4 B loads, 4 MFMA.
//   - per-gk cost: max(producer,consumer) -> (gather+mfma)/allwaves.
// P0 (16-wave, window-sourced), P1, stage: R16-proven, unchanged.
// Accumulation per output (gk asc via gkl, ks asc) -> bit-identical.
// LDS: 114688 (s_xw) + 18432 (s_val dbuf, s_om aliased) + 18432 (s_cw)
//      + 4608 (s_pk) = 156160 B -> 1 block/CU, 16 waves.
// ---------------------------------------------------------------------------
__global__ __launch_bounds__(1024, 4) void dcn_fused(const unsigned short* __restrict__ xt,
                                                     const unsigned short* __restrict__ owf,
                                                     const float* __restrict__ ob,
                                                     const unsigned short* __restrict__ wt2,
                                                     float* __restrict__ out) {
    __shared__ __align__(16) unsigned short s_xw[7 * 64 * 16 * 8];   // 114688 B window
    __shared__ __align__(16) unsigned short s_val[2][64 * PITCH];    // 18432 B dbuf
    __shared__ float4 s_cw[18][64];                                  // 18432 B
    __shared__ int    s_pk[18][64];                                  // 4608 B

    unsigned short* s_om = &s_val[0][0];     // alias: s_om (7128 B) lives pre-P2

    const int t  = threadIdx.x;              // [0,1024)
    const int id = blockIdx.x;               // [0,512)
    const int b  = id & 7;                   // XCD-aware: batch b -> XCD b
    const int ho = id >> 3;                  // full output row

    const int lane = t & 63;
    const int wv   = t >> 6;                 // wave id 0..15
    const int lr   = lane & 15;              // MFMA row/col part
    const int lk   = (lane >> 4) * 8;        // MFMA k offset (shorts)
    const int q    = lane >> 4;              // D row quad

    const int lo = max(0, ho - 3);
    const int hi = min(Hn - 1, ho + 3);
    const int nrows = hi - lo + 1;           // <= 7

    const unsigned short* xb0 = xt + (size_t)b * (Hn * Wn * Cn);
    const short8 zz = {0, 0, 0, 0, 0, 0, 0, 0};

    // ---- S: stage x window rows [lo,hi] into LDS (swizzled chunks) ----
    for (int e = t; e < nrows * 1024; e += 1024) {
        int rs  = e >> 10;                   // row slot
        int rem = e & 1023;                  // x*16 + k
        int xx  = rem >> 4;
        int k   = rem & 15;
        short8 v = *(const short8*)&xb0[(((size_t)(lo + rs) * Wn + xx) * Cn) + k * 8];
        *(short8*)&s_xw[(((rs * 64 + xx) * 16) + (k ^ (xx & 15))) * 8] = v;
    }
    __syncthreads();

    // ---- P0: offset-conv GEMM on ALL 16 waves, A from LDS window ----
    {
        const int cg = wv >> 3;              // conv/deform group
        const int rh4 = (wv >> 1) & 3;       // row quarter (pos base rh4*16)
        const int nh = wv & 1;               // oc 16-block
        const int oc_l = nh * 16 + lr;
        float bias = (oc_l < 27) ? ob[cg * 27 + oc_l] : 0.f;
        f32x4 oacc = (f32x4){bias, bias, bias, bias};

        const unsigned short* wf = owf + (size_t)cg * 18432;

        for (int tap = 0; tap < 9; ++tap) {
            int ky = tap / 3, kx = tap - ky * 3;
            int y = ho - 2 + 2 * ky;
            if (y < 0 || y >= Hn) continue;  // wave-uniform skip (zero pad)
            int slot = y - lo;               // y in [lo,hi] guaranteed
#pragma unroll
            for (int ch = 0; ch < 2; ++ch) {
                int kssl = tap * 2 + ch;
                short8 bv = *(const short8*)&wf[(size_t)kssl * 1024 + nh * 512 + lane * 8];
                int wo = rh4 * 16 + lr;
                int xc = wo - 2 + 2 * kx;
                bool vx = (xc >= 0) & (xc < Wn);
                int xcc = min(max(xc, 0), Wn - 1);
                int kk  = (cg * 8 + ch * 4 + (lane >> 4)) ^ (xcc & 15);
                short8 av = *(const short8*)&s_xw[(((slot * 64 + xcc) * 16) + kk) * 8];
                av = vx ? av : zz;
                oacc = __builtin_amdgcn_mfma_f32_16x16x32_bf16(av, bv, oacc, 0, 0, 0);
            }
        }
        if (oc_l < 27) {
            int c54 = cg * 27 + oc_l;
#pragma unroll
            for (int r = 0; r < 4; ++r)
                s_om[c54 * OMP3 + rh4 * 16 + q * 4 + r] = f2bf(oacc[r]);
        }
    }
    __syncthreads();

    // ---- P1: sampling params for all (gk, pos) of this row ----
    for (int e = t; e < 18 * 64; e += 1024) {
        int pos = e & 63;
        int wo  = pos;
        int gk  = e >> 6;
        int g  = gk / 9, k = gk - g * 9;
        int ky = k / 3,  kx = k - ky * 3;
        float offy = bf2f(s_om[(g * 18 + k * 2 + 0) * OMP3 + pos]);
        float offx = bf2f(s_om[(g * 18 + k * 2 + 1) * OMP3 + pos]);
        float mk   = bf2f(s_om[(36 + g * 9 + k) * OMP3 + pos]);
        mk = 2.0f / (1.0f + __expf(-mk));

        float py = offy + (float)(ky * 2 + ho - 2);
        float px = offx + (float)(kx * 2 + wo - 2);
        float fy = floorf(py), fx = floorf(px);
        int   y0 = (int)fy,    x0 = (int)fx;
        float wy = py - fy,    wx = px - fx;

        bool vy0 = (y0 >= 0) & (y0 < Hn);
        bool vy1 = (y0 + 1 >= 0) & (y0 + 1 < Hn);
        bool vx0 = (x0 >= 0) & (x0 < Wn);
        bool vx1 = (x0 + 1 >= 0) & (x0 + 1 < Wn);
        float4 cw;
        cw.x = (vy0 & vx0) ? (1.f - wy) * (1.f - wx) * mk : 0.f;
        cw.y = (vy0 & vx1) ? (1.f - wy) * wx * mk : 0.f;
        cw.z = (vy1 & vx0) ? wy * (1.f - wx) * mk : 0.f;
        cw.w = (vy1 & vx1) ? wy * wx * mk : 0.f;

        int y0c = min(max(y0, 0), Hn - 1);
        int y1c = min(max(y0 + 1, 0), Hn - 1);
        int x0c = min(max(x0, 0), Wn - 1);
        int x1c = min(max(x0 + 1, 0), Wn - 1);
        s_cw[gk][pos] = cw;
        s_pk[gk][pos] = y0c | (y1c << 8) | (x0c << 16) | (x1c << 24);
    }
    __syncthreads();   // also fences s_om -> s_val reuse

    // ---- P2: pair loop; 1024 threads gather 2 gk, then 16 waves MFMA ----
    const int half = t >> 9;                 // which gk of the pair this thread fills
    const int tl   = t & 511;
    const int pos  = tl >> 3;                // 0..63
    const int c8   = tl & 7;                 // 8-ch chunk id

    const int rh4m = wv >> 2;                // MFMA: mt (row 16-block) 0..3
    const int np   = wv & 3;                 // MFMA: oc-32 group 0..3

    f32x4 acc[2];                            // j = oc-16 within the oc-32
    acc[0] = (f32x4){0.f, 0.f, 0.f, 0.f};
    acc[1] = (f32x4){0.f, 0.f, 0.f, 0.f};

    for (int gkp = 0; gkp < 9; ++gkp) {
        // ---- gather this thread-half's gk of the pair ----
        {
            const int gkj = gkp * 2 + half;
            const int g   = (gkj >= 9) ? 1 : 0;
            float4 cw = s_cw[gkj][pos];
            int pk  = s_pk[gkj][pos];
            int y0c = pk & 255, y1c = (pk >> 8) & 255;
            int x0c = (pk >> 16) & 255, x1c = (pk >> 24) & 255;

            short8 a00, a01, a10, a11;
            bool ok = (y0c >= lo) & (y1c <= hi);
            if (__all(ok)) {
                const int kg = g * 8 + c8;
                a00 = *(const short8*)&s_xw[((((y0c - lo) * 64 + x0c) * 16) + (kg ^ (x0c & 15))) * 8];
                a01 = *(const short8*)&s_xw[((((y0c - lo) * 64 + x1c) * 16) + (kg ^ (x1c & 15))) * 8];
                a10 = *(const short8*)&s_xw[((((y1c - lo) * 64 + x0c) * 16) + (kg ^ (x0c & 15))) * 8];
                a11 = *(const short8*)&s_xw[((((y1c - lo) * 64 + x1c) * 16) + (kg ^ (x1c & 15))) * 8];
            } else {
                const unsigned short* xb = xb0 + g * Cgn + c8 * 8;
                a00 = *(const short8*)&xb[((size_t)y0c * Wn + x0c) * Cn];
                a01 = *(const short8*)&xb[((size_t)y0c * Wn + x1c) * Cn];
                a10 = *(const short8*)&xb[((size_t)y1c * Wn + x0c) * Cn];
                a11 = *(const short8*)&xb[((size_t)y1c * Wn + x1c) * Cn];
            }
            short8 h0;
#pragma unroll
            for (int i = 0; i < 8; ++i) {
                float v = cw.x * bf2f((unsigned short)a00[i]) +
                          cw.y * bf2f((unsigned short)a01[i]) +
                          cw.z * bf2f((unsigned short)a10[i]) +
                          cw.w * bf2f((unsigned short)a11[i]);
                h0[i] = (short)f2bf(v);
            }
            *(short8*)&s_val[half][pos * PITCH + c8 * 8] = h0;
        }
        __syncthreads();                     // both pair tiles ready

        // ---- MFMA: all 16 waves, both gk of the pair (gk asc, ks asc) ----
#pragma unroll
        for (int gkl = 0; gkl < 2; ++gkl) {
            const unsigned short* wf = wt2 + (size_t)(gkp * 2 + gkl) * 8192;
#pragma unroll
            for (int ks = 0; ks < 2; ++ks) {
                short8 af = *(const short8*)&s_val[gkl][(rh4m * 16 + lr) * PITCH + ks * 32 + lk];
#pragma unroll
                for (int j = 0; j < 2; ++j) {
                    short8 bfr = *(const short8*)&wf[(size_t)(ks * 8 + np * 2 + j) * 512 + lane * 8];
                    acc[j] = __builtin_amdgcn_mfma_f32_16x16x32_bf16(af, bfr, acc[j], 0, 0, 0);
                }
            }
        }
        __syncthreads();                     // pair consumed; safe to rewrite
    }

    // ---- epilogue: oc = (np*2+j)*16 + lr; rows rh4m*16 + q*4 ----
#pragma unroll
    for (int j = 0; j < 2; ++j) {
        int oc = (np * 2 + j) * 16 + lr;
        int p0 = rh4m * 16 + q * 4;
        float4 v = {acc[j][0], acc[j][1], acc[j][2], acc[j][3]};
        *(float4*)&out[(((size_t)b * Con + oc) * HOn + ho) * WOn + p0] = v;
    }
}

// ---------------------------------------------------------------------------
extern "C" void kernel_launch(void* const* d_in, const int* in_sizes, int n_in,
                              void* d_out, int out_size, void* d_ws, size_t ws_size,
                              hipStream_t stream) {
    const float* x  = (const float*)d_in[0];   // [8,128,64,64]
    const float* ow = (const float*)d_in[1];   // [54,64,3,3]
    const float* ob = (const float*)d_in[2];   // [54]
    const float* w  = (const float*)d_in[3];   // [128,128,3,3]
    float* out = (float*)d_out;                // [8,128,64,64]

    // ws: x_t bf16 8,388,608 | wt2 294,912 | owf 73,728
    unsigned short* xt  = (unsigned short*)d_ws;
    unsigned short* wt2 = (unsigned short*)((char*)d_ws + 8388608);
    unsigned short* owf = (unsigned short*)((char*)d_ws + 8388608 + 294912);

    hipLaunchKernelGGL(prep, dim3(1232), dim3(256), 0, stream,
                       x, w, ow, xt, wt2, owf);
    hipLaunchKernelGGL(dcn_fused, dim3(512), dim3(1024), 0, stream,
                       xt, owf, ob, wt2, out);
}

// Round 10
// 112.201 us; speedup vs baseline: 1.0983x; 1.0983x over previous
//
#include <hip/hip_runtime.h>
#include <hip/hip_bf16.h>

// Problem constants
static constexpr int Bn = 8, Cn = 128, Hn = 64, Wn = 64, Con = 128;
static constexpr int KKn = 9, DGn = 2, Cgn = 64;
static constexpr int HOn = 64, WOn = 64;
static constexpr int PITCH = 72;     // bf16 row pitch for s_val rows
static constexpr int OMP3 = 66;      // s_om row pitch (shorts), 64 pos + pad

typedef short short8 __attribute__((ext_vector_type(8)));
typedef float f32x4  __attribute__((ext_vector_type(4)));

__device__ __forceinline__ unsigned short f2bf(float f) {
    unsigned u = __float_as_uint(f);
    u += 0x7fff + ((u >> 16) & 1);          // round-to-nearest-even
    return (unsigned short)(u >> 16);
}
__device__ __forceinline__ float bf2f(unsigned short h) {
    return __uint_as_float(((unsigned)h) << 16);
}

// ---------------------------------------------------------------------------
// Kernel P (R18): WEIGHTS-ONLY prep. The x NCHW->NHWC transpose kernel is
// deleted — dcn's window stage now transposes+converts on the fly from x.
// Saves a full global round-trip of x (read 16.8MB + write 8.4MB + re-read)
// and 512 of 1232 prep blocks.
// Blocks [0,576):   main weight -> MFMA B-frag order wt2[gk][ks][tile][lane][8].
// Blocks [576,720): offset weight -> owf[g][ks=tap*2+ch][nt][lane][8].
// ---------------------------------------------------------------------------
__global__ __launch_bounds__(256) void prep(const float* __restrict__ w,
                                            const float* __restrict__ ow,
                                            unsigned short* __restrict__ wt2,
                                            unsigned short* __restrict__ owf) {
    const int blk = blockIdx.x;
    const int t = threadIdx.x;
    if (blk < 576) {
        int e    = blk * 256 + t;                // [0,147456)
        int j    = e & 7;
        int lane = (e >> 3) & 63;
        int tile = (e >> 9) & 7;
        int ks   = (e >> 12) & 1;
        int gk   = e >> 13;                      // 0..17
        int g = gk / 9, k = gk - g * 9;
        int oc = tile * 16 + (lane & 15);
        int c  = ks * 32 + (lane >> 4) * 8 + j;
        wt2[e] = f2bf(w[((size_t)oc * Cn + g * Cgn + c) * KKn + k]);
    } else {
        int e = (blk - 576) * 256 + t;           // [0,36864)
        int g  = e / 18432;
        int r  = e - g * 18432;
        int ks = r >> 10;
        int r2 = r & 1023;
        int nt = r2 >> 9;
        int lane = (r2 >> 3) & 63;
        int j  = r2 & 7;
        int tap = ks >> 1, chalf = ks & 1;
        int oc_l = nt * 16 + (lane & 15);
        int c = chalf * 32 + (lane >> 4) * 8 + j;
        float v = 0.f;
        if (oc_l < 27)
            v = ow[((size_t)(g * 27 + oc_l) * Cgn + c) * KKn + tap];
        owf[e] = f2bf(v);
    }
}

// ---------------------------------------------------------------------------
// Kernel 2 (R18): R16 structure (best proven: 47.7us; overlap worth +11us
// vs lockstep per R17) + on-the-fly window stage from NCHW x.
//   - Stage: chunk (rs,xx,kk) reads its 8 channels straight from x (lanes
//     sweep xx -> 256B coalesced per j; x is L3-resident), f2bf, write to
//     the same swizzled s_xw layout -> s_xw contents bit-identical to R16.
//   - P0 (16-wave, window-sourced), P1: R16 verbatim.
//   - P2: R16 producer/consumer verbatim (waves 0-7 gather, 8-15 MFMA with
//     rh2/nt2 diet), EXCEPT the rare out-of-window fallback reads NCHW x
//     (scalar, correctness-only path).
// Accumulation per output (gk asc, ks asc) unchanged -> bit-identical.
// LDS: 114688 (s_xw) + 18432 (s_val dbuf, s_om aliased) + 18432 (s_cw)
//      + 4608 (s_pk) = 156160 B -> 1 block/CU, 16 waves.
// ---------------------------------------------------------------------------
__global__ __launch_bounds__(1024, 4) void dcn_fused(const float* __restrict__ x,
                                                     const unsigned short* __restrict__ owf,
                                                     const float* __restrict__ ob,
                                                     const unsigned short* __restrict__ wt2,
                                                     float* __restrict__ out) {
    __shared__ __align__(16) unsigned short s_xw[7 * 64 * 16 * 8];   // 114688 B window
    __shared__ __align__(16) unsigned short s_val[2][64 * PITCH];    // 18432 B dbuf
    __shared__ float4 s_cw[18][64];                                  // 18432 B
    __shared__ int    s_pk[18][64];                                  // 4608 B

    unsigned short* s_om = &s_val[0][0];     // alias: s_om (7128 B) lives pre-P2

    const int t  = threadIdx.x;              // [0,1024)
    const int id = blockIdx.x;               // [0,512)
    const int b  = id & 7;                   // XCD-aware: batch b -> XCD b
    const int ho = id >> 3;                  // full output row

    const int lane = t & 63;
    const int wv   = t >> 6;                 // wave id 0..15
    const int lr   = lane & 15;              // MFMA row/col part
    const int lk   = (lane >> 4) * 8;        // MFMA k offset (shorts)
    const int q    = lane >> 4;              // D row quad

    const int lo = max(0, ho - 3);
    const int hi = min(Hn - 1, ho + 3);
    const int nrows = hi - lo + 1;           // <= 7

    const float* xb4 = x + (size_t)b * Cn * Hn * Wn;   // NCHW batch base
    const short8 zz = {0, 0, 0, 0, 0, 0, 0, 0};

    // ---- S: stage x window rows [lo,hi] into LDS, transposing on the fly ----
    // chunk u: xx = u&63 (lane-consecutive -> coalesced), kk = (u>>6)&15, rs = u>>10.
    for (int u = t; u < nrows * 1024; u += 1024) {
        int xx = u & 63;
        int kk = (u >> 6) & 15;
        int rs = u >> 10;
        int y  = lo + rs;
        short8 v;
#pragma unroll
        for (int j = 0; j < 8; ++j) {
            float f = xb4[(((size_t)(kk * 8 + j) * Hn) + y) * Wn + xx];
            v[j] = (short)f2bf(f);
        }
        *(short8*)&s_xw[(((rs * 64 + xx) * 16) + (kk ^ (xx & 15))) * 8] = v;
    }
    __syncthreads();

    // ---- P0: offset-conv GEMM on ALL 16 waves, A from LDS window ----
    {
        const int cg = wv >> 3;              // conv/deform group
        const int rh4 = (wv >> 1) & 3;       // row quarter (pos base rh4*16)
        const int nh = wv & 1;               // oc 16-block
        const int oc_l = nh * 16 + lr;
        float bias = (oc_l < 27) ? ob[cg * 27 + oc_l] : 0.f;
        f32x4 oacc = (f32x4){bias, bias, bias, bias};

        const unsigned short* wf = owf + (size_t)cg * 18432;

        for (int tap = 0; tap < 9; ++tap) {
            int ky = tap / 3, kx = tap - ky * 3;
            int y = ho - 2 + 2 * ky;
            if (y < 0 || y >= Hn) continue;  // wave-uniform skip (zero pad)
            int slot = y - lo;               // y in [lo,hi] guaranteed
#pragma unroll
            for (int ch = 0; ch < 2; ++ch) {
                int kssl = tap * 2 + ch;
                short8 bv = *(const short8*)&wf[(size_t)kssl * 1024 + nh * 512 + lane * 8];
                int wo = rh4 * 16 + lr;
                int xc = wo - 2 + 2 * kx;
                bool vx = (xc >= 0) & (xc < Wn);
                int xcc = min(max(xc, 0), Wn - 1);
                int kk  = (cg * 8 + ch * 4 + (lane >> 4)) ^ (xcc & 15);
                short8 av = *(const short8*)&s_xw[(((slot * 64 + xcc) * 16) + kk) * 8];
                av = vx ? av : zz;
                oacc = __builtin_amdgcn_mfma_f32_16x16x32_bf16(av, bv, oacc, 0, 0, 0);
            }
        }
        if (oc_l < 27) {
            int c54 = cg * 27 + oc_l;
#pragma unroll
            for (int r = 0; r < 4; ++r)
                s_om[c54 * OMP3 + rh4 * 16 + q * 4 + r] = f2bf(oacc[r]);
        }
    }
    __syncthreads();

    // ---- P1: sampling params for all (gk, pos) of this row ----
    for (int e = t; e < 18 * 64; e += 1024) {
        int pos = e & 63;
        int wo  = pos;
        int gk  = e >> 6;
        int g  = gk / 9, k = gk - g * 9;
        int ky = k / 3,  kx = k - ky * 3;
        float offy = bf2f(s_om[(g * 18 + k * 2 + 0) * OMP3 + pos]);
        float offx = bf2f(s_om[(g * 18 + k * 2 + 1) * OMP3 + pos]);
        float mk   = bf2f(s_om[(36 + g * 9 + k) * OMP3 + pos]);
        mk = 2.0f / (1.0f + __expf(-mk));

        float py = offy + (float)(ky * 2 + ho - 2);
        float px = offx + (float)(kx * 2 + wo - 2);
        float fy = floorf(py), fx = floorf(px);
        int   y0 = (int)fy,    x0 = (int)fx;
        float wy = py - fy,    wx = px - fx;

        bool vy0 = (y0 >= 0) & (y0 < Hn);
        bool vy1 = (y0 + 1 >= 0) & (y0 + 1 < Hn);
        bool vx0 = (x0 >= 0) & (x0 < Wn);
        bool vx1 = (x0 + 1 >= 0) & (x0 + 1 < Wn);
        float4 cw;
        cw.x = (vy0 & vx0) ? (1.f - wy) * (1.f - wx) * mk : 0.f;
        cw.y = (vy0 & vx1) ? (1.f - wy) * wx * mk : 0.f;
        cw.z = (vy1 & vx0) ? wy * (1.f - wx) * mk : 0.f;
        cw.w = (vy1 & vx1) ? wy * wx * mk : 0.f;

        int y0c = min(max(y0, 0), Hn - 1);
        int y1c = min(max(y0 + 1, 0), Hn - 1);
        int x0c = min(max(x0, 0), Wn - 1);
        int x1c = min(max(x0 + 1, 0), Wn - 1);
        s_cw[gk][pos] = cw;
        s_pk[gk][pos] = y0c | (y1c << 8) | (x0c << 16) | (x1c << 24);
    }
    __syncthreads();   // also fences s_om -> s_val reuse

    // ---- P2: producer/consumer gk loop (R16 verbatim), one barrier per gk ----
    auto gather_tile = [&](int gkj) {
        const int pos = t >> 3;              // 0..63 (t < 512)
        const int c8  = t & 7;               // 8-ch chunk id
        const int g   = (gkj >= 9) ? 1 : 0;
        float4 cw = s_cw[gkj][pos];
        int pk  = s_pk[gkj][pos];
        int y0c = pk & 255, y1c = (pk >> 8) & 255;
        int x0c = (pk >> 16) & 255, x1c = (pk >> 24) & 255;

        short8 a00, a01, a10, a11;
        bool ok = (y0c >= lo) & (y1c <= hi);
        if (__all(ok)) {
            const int kg = g * 8 + c8;
            a00 = *(const short8*)&s_xw[((((y0c - lo) * 64 + x0c) * 16) + (kg ^ (x0c & 15))) * 8];
            a01 = *(const short8*)&s_xw[((((y0c - lo) * 64 + x1c) * 16) + (kg ^ (x1c & 15))) * 8];
            a10 = *(const short8*)&s_xw[((((y1c - lo) * 64 + x0c) * 16) + (kg ^ (x0c & 15))) * 8];
            a11 = *(const short8*)&s_xw[((((y1c - lo) * 64 + x1c) * 16) + (kg ^ (x1c & 15))) * 8];
        } else {
            // rare fallback (offsets beyond window): read NCHW x directly,
            // f2bf -> values bit-identical to the staged path.
            const float* xc0 = xb4 + (size_t)(g * Cgn + c8 * 8) * Hn * Wn;
#pragma unroll
            for (int j = 0; j < 8; ++j) {
                const float* xj = xc0 + (size_t)j * Hn * Wn;
                a00[j] = (short)f2bf(xj[(size_t)y0c * Wn + x0c]);
                a01[j] = (short)f2bf(xj[(size_t)y0c * Wn + x1c]);
                a10[j] = (short)f2bf(xj[(size_t)y1c * Wn + x0c]);
                a11[j] = (short)f2bf(xj[(size_t)y1c * Wn + x1c]);
            }
        }
        short8 h0;
#pragma unroll
        for (int i = 0; i < 8; ++i) {
            float v = cw.x * bf2f((unsigned short)a00[i]) +
                      cw.y * bf2f((unsigned short)a01[i]) +
                      cw.z * bf2f((unsigned short)a10[i]) +
                      cw.w * bf2f((unsigned short)a11[i]);
            h0[i] = (short)f2bf(v);
        }
        *(short8*)&s_val[gkj & 1][pos * PITCH + c8 * 8] = h0;
    };

    f32x4 acc[2][2];                         // [i = mt in pair][j = oc-16 in pair]
#pragma unroll
    for (int i = 0; i < 2; ++i)
#pragma unroll
        for (int j = 0; j < 2; ++j) acc[i][j] = (f32x4){0.f, 0.f, 0.f, 0.f};

    if (wv < 8) gather_tile(0);              // prologue fill buf0

    const int cid = wv - 8;                  // consumer id 0..7 (wv >= 8)
    const int rh2 = cid >> 2;                // mt pair: rows (rh2*2+i)*16
    const int nt2 = cid & 3;                 // oc-32: tiles nt2*2 + j

    for (int gk = 0; gk < 18; ++gk) {
        __syncthreads();                     // s_val[gk&1] ready for consumers
        if (wv < 8) {
            if (gk < 17) gather_tile(gk + 1);   // fill other buffer concurrently
        } else {
            const unsigned short* wf = wt2 + (size_t)gk * 8192;
#pragma unroll
            for (int ks = 0; ks < 2; ++ks) {
                short8 af[2];
#pragma unroll
                for (int i = 0; i < 2; ++i)
                    af[i] = *(const short8*)&s_val[gk & 1][((rh2 * 2 + i) * 16 + lr) * PITCH + ks * 32 + lk];
#pragma unroll
                for (int i = 0; i < 2; ++i)
#pragma unroll
                    for (int j = 0; j < 2; ++j) {
                        short8 bfr = *(const short8*)&wf[(size_t)(ks * 8 + nt2 * 2 + j) * 512 + lane * 8];
                        acc[i][j] = __builtin_amdgcn_mfma_f32_16x16x32_bf16(af[i], bfr, acc[i][j], 0, 0, 0);
                    }
            }
        }
    }

    // ---- epilogue (consumers): oc = (nt2*2+j)*16 + lr; rows (rh2*2+i)*16 + q*4 ----
    if (wv >= 8) {
#pragma unroll
        for (int i = 0; i < 2; ++i)
#pragma unroll
            for (int j = 0; j < 2; ++j) {
                int oc = (nt2 * 2 + j) * 16 + lr;
                int p0 = (rh2 * 2 + i) * 16 + q * 4;
                float4 v = {acc[i][j][0], acc[i][j][1], acc[i][j][2], acc[i][j][3]};
                *(float4*)&out[(((size_t)b * Con + oc) * HOn + ho) * WOn + p0] = v;
            }
    }
}

// ---------------------------------------------------------------------------
extern "C" void kernel_launch(void* const* d_in, const int* in_sizes, int n_in,
                              void* d_out, int out_size, void* d_ws, size_t ws_size,
                              hipStream_t stream) {
    const float* x  = (const float*)d_in[0];   // [8,128,64,64]
    const float* ow = (const float*)d_in[1];   // [54,64,3,3]
    const float* ob = (const float*)d_in[2];   // [54]
    const float* w  = (const float*)d_in[3];   // [128,128,3,3]
    float* out = (float*)d_out;                // [8,128,64,64]

    // ws: wt2 294,912 | owf 73,728 (xt eliminated)
    unsigned short* wt2 = (unsigned short*)d_ws;
    unsigned short* owf = (unsigned short*)((char*)d_ws + 294912);

    hipLaunchKernelGGL(prep, dim3(720), dim3(256), 0, stream,
                       w, ow, wt2, owf);
    hipLaunchKernelGGL(dcn_fused, dim3(512), dim3(1024), 0, stream,
                       x, owf, ob, wt2, out);
}